// Round 1
// baseline (117.599 us; speedup 1.0000x reference)
//
#include <hip/hip_runtime.h>

// DetectionLayer (YOLO head decode), fp32.
// x:      (B=32, C=255, G=76, G=76)  where C = a*85 + k, k in [0,85)
// out:    (B, 3*76*76, 85)
// Per (b,a): transpose 85 x 5776 -> 5776 x 85 with per-k elementwise math.
//   k=0: (sigmoid(v)+gx)*stride      k=1: (sigmoid(v)+gy)*stride
//   k=2: exp(v)*anchors[a].w         k=3: exp(v)*anchors[a].h
//        (scaled_anchor = anchors/stride, box *= stride -> cancels)
//   k>=4: sigmoid(v)

#define GDIM   76
#define GG     5776      // 76*76
#define NC     85        // 80 classes + 5
#define NA     3
#define NCH    255       // NA*NC
#define NCELLS 17328     // NA*GG
#define STRIDEF 8.0f     // 608/76
#define TC     128       // cells per tile
#define NTILE  46        // ceil(5776/128); last tile has 16 cells

__device__ __forceinline__ float sigf(float v) {
    return 1.0f / (1.0f + __expf(-v));
}

__global__ __launch_bounds__(256)
void det_decode_kernel(const float* __restrict__ x,
                       const float* __restrict__ anchors,
                       float* __restrict__ out) {
    __shared__ float lds[TC * NC];   // [cell][k], stride 85 (odd -> conflict-friendly)

    const int blk  = blockIdx.x;
    const int tile = blk % NTILE;
    const int ba   = blk / NTILE;
    const int a    = ba % NA;
    const int b    = ba / NA;

    const int s0    = tile * TC;
    const int ncell = (GG - s0 < TC) ? (GG - s0) : TC;   // 128 or 16

    const float aw = anchors[2 * a];
    const float ah = anchors[2 * a + 1];

    const float* __restrict__ src = x + (size_t)(b * NCH + a * NC) * GG + s0;

    if (ncell == TC) {
        // Phase 1: for each k (85), read 128 cells as 32 float4 (coalesced),
        // apply math, scatter into lds[cell*85 + k].
        for (int e = threadIdx.x; e < NC * (TC / 4); e += 256) {
            const int k    = e >> 5;        // /32
            const int c4   = e & 31;
            const int cell = c4 * 4;
            const float4 v = *reinterpret_cast<const float4*>(src + (size_t)k * GG + cell);
            float vv[4] = {v.x, v.y, v.z, v.w};
            #pragma unroll
            for (int j = 0; j < 4; ++j) {
                const int s = s0 + cell + j;
                const float val = vv[j];
                float r;
                if (k == 0) {
                    const int gx = s % GDIM;
                    r = (sigf(val) + (float)gx) * STRIDEF;
                } else if (k == 1) {
                    const int gy = s / GDIM;
                    r = (sigf(val) + (float)gy) * STRIDEF;
                } else if (k == 2) {
                    r = __expf(val) * aw;
                } else if (k == 3) {
                    r = __expf(val) * ah;
                } else {
                    r = sigf(val);
                }
                lds[(cell + j) * NC + k] = r;
            }
        }
    } else {
        // Edge tile (16 cells).
        for (int e = threadIdx.x; e < NC * 16; e += 256) {
            const int k    = e >> 4;
            const int cell = e & 15;
            const int s    = s0 + cell;
            const float val = src[(size_t)k * GG + cell];
            float r;
            if (k == 0) {
                r = (sigf(val) + (float)(s % GDIM)) * STRIDEF;
            } else if (k == 1) {
                r = (sigf(val) + (float)(s / GDIM)) * STRIDEF;
            } else if (k == 2) {
                r = __expf(val) * aw;
            } else if (k == 3) {
                r = __expf(val) * ah;
            } else {
                r = sigf(val);
            }
            lds[cell * NC + k] = r;
        }
    }

    __syncthreads();

    // Phase 2: output tile is ncell*85 contiguous floats; lds[cell][k] is the
    // same linear order -> linear copy, coalesced float4 stores.
    float* __restrict__ dst = out + (size_t)(b * NCELLS + a * GG + s0) * NC;
    const int ntot = ncell * NC;                 // 10880 or 1360, both %4==0
    for (int t = threadIdx.x; t < (ntot >> 2); t += 256) {
        *reinterpret_cast<float4*>(dst + 4 * t) =
            *reinterpret_cast<const float4*>(lds + 4 * t);
    }
}

extern "C" void kernel_launch(void* const* d_in, const int* in_sizes, int n_in,
                              void* d_out, int out_size, void* d_ws, size_t ws_size,
                              hipStream_t stream) {
    const float* x       = (const float*)d_in[0];
    const float* anchors = (const float*)d_in[1];
    float* out           = (float*)d_out;

    const int B = 32;
    const int nblocks = B * NA * NTILE;   // 32*3*46 = 4416
    det_decode_kernel<<<dim3(nblocks), dim3(256), 0, stream>>>(x, anchors, out);
}

// Round 4
// 66.696 us; speedup vs baseline: 1.7632x; 1.7632x over previous
//
#include <hip/hip_runtime.h>

// DetectionLayer (YOLO head decode), fp32.
// x:   (B=32, C=255, G=76, G=76)  where C = a*85 + k, k in [0,85)
// out: (B, 3*76*76, 85)
// Per (b,a): transpose 85 x 5776 -> 5776 x 85 with per-k elementwise math.
//   k=0: (sigmoid(v)+gx)*stride      k=1: (sigmoid(v)+gy)*stride
//   k=2: exp(v)*anchors[a].w         k=3: exp(v)*anchors[a].h   (stride cancels)
//   k>=4: sigmoid(v)
//
// Tile = 64 cells -> LDS 21.76 KB -> 7 blocks/CU (28 waves/CU, was 3 blocks/12 waves).
// Phase-1 lane map (c4 = e&15, k = e>>4): per wave, banks (20*c4 + k) mod 32
// cover 32 distinct banks x 2 lanes = free 2-way -> no conflicts, no swizzle.
// Phase-2 output tile is contiguous; LDS [cell][85] is the same linear order.

#define GDIM   76
#define GG     5776      // 76*76
#define NC     85        // 80 classes + 5
#define NA     3
#define NCH    255       // NA*NC
#define NCELLS 17328     // NA*GG
#define STRIDEF 8.0f     // 608/76
#define TC     64        // cells per tile
#define NTILE  91        // ceil(5776/64); last tile has 16 cells

typedef float f32x4 __attribute__((ext_vector_type(4)));   // native vec for nontemporal

__device__ __forceinline__ float sigf(float v) {
    return 1.0f / (1.0f + __expf(-v));
}

__device__ __forceinline__ float decode(float val, int k, int s, float aw, float ah) {
    if (k == 0)      return (sigf(val) + (float)(s % GDIM)) * STRIDEF;
    else if (k == 1) return (sigf(val) + (float)(s / GDIM)) * STRIDEF;
    else if (k == 2) return __expf(val) * aw;
    else if (k == 3) return __expf(val) * ah;
    else             return sigf(val);
}

__global__ __launch_bounds__(256)
void det_decode_kernel(const float* __restrict__ x,
                       const float* __restrict__ anchors,
                       float* __restrict__ out) {
    __shared__ float lds[TC * NC];   // [cell][k], linear

    const int blk  = blockIdx.x;
    const int tile = blk % NTILE;
    const int ba   = blk / NTILE;
    const int a    = ba % NA;
    const int b    = ba / NA;

    const int s0    = tile * TC;
    const int ncell = (GG - s0 < TC) ? (GG - s0) : TC;   // 64 or 16

    const float aw = anchors[2 * a];
    const float ah = anchors[2 * a + 1];

    const float* __restrict__ src = x + (size_t)(b * NCH + a * NC) * GG + s0;

    if (ncell == TC) {
        // 85 k-rows x 16 float4 (=64 cells). Wave64 = 4 k-rows x 16 quads:
        // coalesced 256B-per-k loads; LDS writes land 2-way (free).
        for (int e = threadIdx.x; e < NC * (TC / 4); e += 256) {
            const int k    = e >> 4;        // /16
            const int c4   = e & 15;
            const int cell = c4 * 4;
            const f32x4 v = *reinterpret_cast<const f32x4*>(src + (size_t)k * GG + cell);
            #pragma unroll
            for (int j = 0; j < 4; ++j)
                lds[(cell + j) * NC + k] = decode(v[j], k, s0 + cell + j, aw, ah);
        }
    } else {
        // Edge tile (16 cells): 85 k-rows x 4 quads.
        for (int e = threadIdx.x; e < NC * 4; e += 256) {
            const int k    = e >> 2;
            const int c4   = e & 3;
            const int cell = c4 * 4;
            const f32x4 v = *reinterpret_cast<const f32x4*>(src + (size_t)k * GG + cell);
            #pragma unroll
            for (int j = 0; j < 4; ++j)
                lds[(cell + j) * NC + k] = decode(v[j], k, s0 + cell + j, aw, ah);
        }
    }

    __syncthreads();

    // Output tile = ncell*85 contiguous floats, same linear order as LDS.
    // Non-temporal: output is write-once -> keep LLC for the input.
    float* __restrict__ dst = out + (size_t)(b * NCELLS + a * GG + s0) * NC;
    const int ntot = ncell * NC;                 // 5440 or 1360, both %4==0
    for (int t = threadIdx.x; t < (ntot >> 2); t += 256) {
        const f32x4 v = *reinterpret_cast<const f32x4*>(lds + 4 * t);
        __builtin_nontemporal_store(v, reinterpret_cast<f32x4*>(dst + 4 * t));
    }
}

extern "C" void kernel_launch(void* const* d_in, const int* in_sizes, int n_in,
                              void* d_out, int out_size, void* d_ws, size_t ws_size,
                              hipStream_t stream) {
    const float* x       = (const float*)d_in[0];
    const float* anchors = (const float*)d_in[1];
    float* out           = (float*)d_out;

    const int B = 32;
    const int nblocks = B * NA * NTILE;   // 32*3*91 = 8736
    det_decode_kernel<<<dim3(nblocks), dim3(256), 0, stream>>>(x, anchors, out);
}